// Round 8
// baseline (16.233 us; speedup 1.0000x reference)
//
#include <hip/hip_runtime.h>

namespace {

constexpr int B_ = 4, C_ = 64, H_ = 96, W_ = 192, S_ = 12;
constexpr int HW = H_ * W_;
constexpr float TEMP_OVER_C = 7.0f / 64.0f;   // TEMPERATURE / C
constexpr int OUT_HALF = B_ * 4 * H_ * W_;    // ndisp_out first, then disp_out
constexpr int WBLK = 48;                      // output cols per tile
constexpr int SCOLS = 96;                     // staged right cols (48 + 48 halo)
constexpr int RSTR = 36;  // right: dwords/col per 32-chan chunk (9 slots, odd -> bank spread)
constexpr int LSTRL = 68; // left: dwords/col for 64 chans (17 slots, odd -> bank spread)
// LDS float offsets
constexpr int R0 = 0;
constexpr int R1 = SCOLS * RSTR;              // 3456
constexpr int L0 = 2 * SCOLS * RSTR;          // 6912
constexpr int LDS_FLOATS = L0 + WBLK * LSTRL; // 10176 -> 40704 B -> 4 blocks/CU

__global__ __launch_bounds__(192) void fused_eval(
    const float* __restrict__ left, const float* __restrict__ right,
    const float* __restrict__ disp, const float* __restrict__ ndisp,
    float* __restrict__ out)
{
  __shared__ float lds[LDS_FLOATS];

  // 1536 tiles = 8 XCDs x (48 rows x 4 chunks); wgid%8 -> XCD keeps a row's
  // chunks (and its 48-row band) on one XCD's L2 for halo reuse.
  const int xcd  = blockIdx.x & 7;
  const int slot = blockIdx.x >> 3;      // 0..191
  const int bh   = xcd * 48 + (slot >> 2);
  const int q    = slot & 3;             // row chunk 0..3
  const int b = bh / H_;
  const int h = bh - b * H_;
  const int w0 = q * WBLK;
  const int s0g = q ? (WBLK * q - 48) : 0;   // staged right cols [s0g, s0g+96)

  const int t = threadIdx.x;             // 0..191
  const int l = t & 63;
  const int v = t >> 6;                  // wave 0..2
  const int wl = v * 16 + (l & 15);      // 0..47
  const int sg = (l >> 4) & 3;           // interval 0..3
  const int w  = w0 + wl;

  // staging task decode: right tasks (4col x 4chan tiles): cq 0..23, cg 0..7
  const int cq = t >> 3;
  const int cg = t & 7;
  // left tasks: lcq 0..11, lcg 0..15
  const int lcq = t >> 4;
  const int lcg = t & 15;

  const float* rrow = right + (size_t)b * C_ * HW + (size_t)h * W_ + s0g;
  const float* lrow = left  + (size_t)b * C_ * HW + (size_t)h * W_ + w0;

  // ---- issue float4 staging reads: right chunk0, left, disp, right chunk1 ----
  float4 rt0[4];
  #pragma unroll
  for (int j = 0; j < 4; ++j)
    rt0[j] = *reinterpret_cast<const float4*>(rrow + (size_t)(4*cg + j) * HW + 4*cq);
  float4 lt[4];
  #pragma unroll
  for (int j = 0; j < 4; ++j)
    lt[j] = *reinterpret_cast<const float4*>(lrow + (size_t)(4*lcg + j) * HW + 4*lcq);

  const size_t dbase = ((size_t)(b * S_ + 3 * sg) * H_ + h) * W_ + w;
  float dsp[3];
  #pragma unroll
  for (int k = 0; k < 3; ++k) dsp[k] = disp[dbase + (size_t)k * HW];

  float4 rt1[4];   // chunk1 (chans 32..63): stays in flight through barrier+gather0
  #pragma unroll
  for (int j = 0; j < 4; ++j)
    rt1[j] = *reinterpret_cast<const float4*>(rrow + (size_t)(32 + 4*cg + j) * HW + 4*cq);

  // jdx while loads fly: reference clip(w-d, 0, W-1) f32 then int32 trunc
  int jb[3];
  #pragma unroll
  for (int k = 0; k < 3; ++k) {
    const float ry = fminf(fmaxf((float)w - dsp[k], 0.0f), (float)(W_ - 1));
    jb[k] = ((int)ry - s0g) * RSTR;
  }

  // ---- transpose-write chunk0 + left to LDS (b128, conflict-free) ----
  {
    const float* f0 = reinterpret_cast<const float*>(&rt0[0]);
    const float* f1 = reinterpret_cast<const float*>(&rt0[1]);
    const float* f2 = reinterpret_cast<const float*>(&rt0[2]);
    const float* f3 = reinterpret_cast<const float*>(&rt0[3]);
    float* dst = &lds[R0 + 4*cq*RSTR + 4*cg];
    #pragma unroll
    for (int i = 0; i < 4; ++i)
      *reinterpret_cast<float4*>(dst + i*RSTR) = make_float4(f0[i], f1[i], f2[i], f3[i]);
  }
  {
    const float* f0 = reinterpret_cast<const float*>(&lt[0]);
    const float* f1 = reinterpret_cast<const float*>(&lt[1]);
    const float* f2 = reinterpret_cast<const float*>(&lt[2]);
    const float* f3 = reinterpret_cast<const float*>(&lt[3]);
    float* dst = &lds[L0 + 4*lcq*LSTRL + 4*lcg];
    #pragma unroll
    for (int i = 0; i < 4; ++i)
      *reinterpret_cast<float4*>(dst + i*LSTRL) = make_float4(f0[i], f1[i], f2[i], f3[i]);
  }

  __syncthreads();

  // ndisp: issue now, consumed in epilogue (hides under gather)
  float nds[3];
  #pragma unroll
  for (int k = 0; k < 3; ++k) nds[k] = ndisp[dbase + (size_t)k * HW];

  // ---- gather chunk0 (chans 0..31): left from LDS (broadcast across sg) ----
  float la[32];
  {
    const float* lb = &lds[L0 + wl * LSTRL];
    #pragma unroll
    for (int k = 0; k < 8; ++k)
      *reinterpret_cast<float4*>(&la[4*k]) = *reinterpret_cast<const float4*>(lb + 4*k);
  }
  float st[3] = {0.f, 0.f, 0.f};
  #pragma unroll
  for (int s = 0; s < 3; ++s) {
    const float* rr = &lds[R0 + jb[s]];
    float a = st[s];
    #pragma unroll
    for (int k = 0; k < 8; ++k) {
      const float4 r = *reinterpret_cast<const float4*>(rr + 4*k);
      a = fmaf(la[4*k+0], r.x, a);
      a = fmaf(la[4*k+1], r.y, a);
      a = fmaf(la[4*k+2], r.z, a);
      a = fmaf(la[4*k+3], r.w, a);
    }
    st[s] = a;
  }

  // ---- transpose-write chunk1 (separate LDS region: no pre-barrier needed) ----
  {
    const float* f0 = reinterpret_cast<const float*>(&rt1[0]);
    const float* f1 = reinterpret_cast<const float*>(&rt1[1]);
    const float* f2 = reinterpret_cast<const float*>(&rt1[2]);
    const float* f3 = reinterpret_cast<const float*>(&rt1[3]);
    float* dst = &lds[R1 + 4*cq*RSTR + 4*cg];
    #pragma unroll
    for (int i = 0; i < 4; ++i)
      *reinterpret_cast<float4*>(dst + i*RSTR) = make_float4(f0[i], f1[i], f2[i], f3[i]);
  }

  __syncthreads();

  // ---- gather chunk1 (chans 32..63) ----
  {
    const float* lb = &lds[L0 + wl * LSTRL + 32];
    #pragma unroll
    for (int k = 0; k < 8; ++k)
      *reinterpret_cast<float4*>(&la[4*k]) = *reinterpret_cast<const float4*>(lb + 4*k);
  }
  #pragma unroll
  for (int s = 0; s < 3; ++s) {
    const float* rr = &lds[R1 + jb[s]];
    float a = st[s];
    #pragma unroll
    for (int k = 0; k < 8; ++k) {
      const float4 r = *reinterpret_cast<const float4*>(rr + 4*k);
      a = fmaf(la[4*k+0], r.x, a);
      a = fmaf(la[4*k+1], r.y, a);
      a = fmaf(la[4*k+2], r.z, a);
      a = fmaf(la[4*k+3], r.w, a);
    }
    st[s] = a;
  }

  // ---- epilogue: this thread's one interval, fully static ----
  const float a0 = st[0] * TEMP_OVER_C;
  const float a1 = st[1] * TEMP_OVER_C;
  const float a2 = st[2] * TEMP_OVER_C;
  const float m  = fmaxf(a0, fmaxf(a1, a2));
  const float e0 = __expf(a0 - m);
  const float e1 = __expf(a1 - m);
  const float e2 = __expf(a2 - m);
  const float inv = 1.0f / (e0 + e1 + e2);
  const size_t o = ((size_t)(b * 4 + sg) * H_ + h) * W_ + w;
  out[o]            = (nds[0] * e0 + nds[1] * e1 + nds[2] * e2) * inv;
  out[OUT_HALF + o] = (dsp[0] * e0 + dsp[1] * e1 + dsp[2] * e2) * inv;
}

} // namespace

extern "C" void kernel_launch(void* const* d_in, const int* in_sizes, int n_in,
                              void* d_out, int out_size, void* d_ws, size_t ws_size,
                              hipStream_t stream) {
  const float* left  = (const float*)d_in[0];
  const float* right = (const float*)d_in[1];
  const float* disp  = (const float*)d_in[2];
  const float* ndisp = (const float*)d_in[3];
  float* out = (float*)d_out;
  dim3 grid(8 * 48 * 4);   // 1536 tiles
  dim3 block(192);
  hipLaunchKernelGGL(fused_eval, grid, block, 0, stream, left, right, disp, ndisp, out);
}

// Round 9
// 15.382 us; speedup vs baseline: 1.0553x; 1.0553x over previous
//
#include <hip/hip_runtime.h>

namespace {

constexpr int B_ = 4, C_ = 64, H_ = 96, W_ = 192, S_ = 12;
constexpr int HW = H_ * W_;
constexpr float TEMP_OVER_C = 7.0f / 64.0f;   // TEMPERATURE / C
constexpr int OUT_HALF = B_ * 4 * H_ * W_;    // ndisp_out first, then disp_out
constexpr int LSTR = 68;                      // LDS stride: 68%32=4 -> b128 bank-conflict-free

// pure-LDS gather chunk: no global deps inside
#define GATHER_CHUNK(C0)                                                  \
  {                                                                       \
    _Pragma("unroll")                                                     \
    for (int s = 0; s < 6; ++s) {                                         \
      const float* rr = rp[s] + (C0);                                     \
      const float4 r0 = *reinterpret_cast<const float4*>(rr);             \
      const float4 r1 = *reinterpret_cast<const float4*>(rr + 4);         \
      const float4 r2 = *reinterpret_cast<const float4*>(rr + 8);        \
      const float4 r3 = *reinterpret_cast<const float4*>(rr + 12);        \
      float a = st[s];                                                    \
      a = fmaf(la[(C0)+0],  r0.x, a);  a = fmaf(la[(C0)+1],  r0.y, a);    \
      a = fmaf(la[(C0)+2],  r0.z, a);  a = fmaf(la[(C0)+3],  r0.w, a);    \
      a = fmaf(la[(C0)+4],  r1.x, a);  a = fmaf(la[(C0)+5],  r1.y, a);    \
      a = fmaf(la[(C0)+6],  r1.z, a);  a = fmaf(la[(C0)+7],  r1.w, a);    \
      a = fmaf(la[(C0)+8],  r2.x, a);  a = fmaf(la[(C0)+9],  r2.y, a);    \
      a = fmaf(la[(C0)+10], r2.z, a);  a = fmaf(la[(C0)+11], r2.w, a);    \
      a = fmaf(la[(C0)+12], r3.x, a);  a = fmaf(la[(C0)+13], r3.y, a);    \
      a = fmaf(la[(C0)+14], r3.z, a);  a = fmaf(la[(C0)+15], r3.w, a);    \
      st[s] = a;                                                          \
    }                                                                     \
  }

__global__ __launch_bounds__(192) void fused_eval(
    const float* __restrict__ left, const float* __restrict__ right,
    const float* __restrict__ disp, const float* __restrict__ ndisp,
    float* __restrict__ out)
{
  __shared__ float rlds[144 * LSTR];   // 39168 B -> 4 blocks/CU

  // grid 768: bid and bid+384 are the two halves of one (b,h) row;
  // 384 % 8 == 0 -> pair lands on the same XCD (halo cols hit L2).
  const int bid = blockIdx.x;
  const int half = (bid >= 384) ? 1 : 0;
  const int bh = bid - half * 384;
  const int b = bh / H_;
  const int h = bh - b * H_;
  const int w0 = half * 96;
  const int s0g = half * 48;              // staged right cols: [s0g, s0g + (96|144))

  const int t = threadIdx.x;              // 0..191
  const int shalf = (t >= 96) ? 1 : 0;    // sample half: s 0..5 or 6..11
  const int wl = t - shalf * 96;          // 0..95
  const int w = w0 + wl;

  // ---- staging reads first (they gate the barrier) ----
  // part A (both halves): col=wl, channels [32*shalf, +32) -> coalesced
  const float* rrow = right + (size_t)b * C_ * HW + (size_t)h * W_ + s0g;
  const int cbA = shalf * 32;
  float va[32];
  {
    const float* srcA = rrow + wl;
    #pragma unroll
    for (int j = 0; j < 32; ++j) va[j] = srcA[(size_t)(cbA + j) * HW];
  }
  // part B (half 1 only): cols 96..143, 4 chan-groups, 1 task/thread
  float vb[16];
  int colB = 96, cbB = 0;
  if (half) {
    const int cgB = t / 48;
    colB = 96 + (t - cgB * 48);
    cbB = cgB * 16;
    const float* srcB = rrow + colB;
    #pragma unroll
    for (int j = 0; j < 16; ++j) vb[j] = srcB[(size_t)(cbB + j) * HW];
  }

  // ---- ALL remaining global reads issued pre-barrier: left 64, disp, ndisp.
  //      Post-barrier phase then has ZERO vmcnt dependencies. ----
  const float* lcol = left + (size_t)b * C_ * HW + (size_t)h * W_ + w;
  float la[64];
  #pragma unroll
  for (int c = 0; c < 64; ++c) la[c] = lcol[(size_t)c * HW];

  const int sb = 6 * shalf;
  float dsp[6], nds[6]; int jdx[6];
  const size_t dbase = ((size_t)(b * S_ + sb) * H_ + h) * W_ + w;
  #pragma unroll
  for (int s = 0; s < 6; ++s) {
    dsp[s] = disp[dbase + (size_t)s * HW];
    nds[s] = ndisp[dbase + (size_t)s * HW];
  }
  #pragma unroll
  for (int s = 0; s < 6; ++s) {
    // reference: clip(w - d, 0, W-1) in f32, then int32 truncation
    const float ry = fminf(fmaxf((float)w - dsp[s], 0.0f), (float)(W_ - 1));
    jdx[s] = (int)ry - s0g;
  }

  // ---- LDS writes (transposed [col][chan], b128, conflict-free) ----
  {
    float* dstA = &rlds[wl * LSTR + cbA];
    #pragma unroll
    for (int j = 0; j < 8; ++j)
      *reinterpret_cast<float4*>(dstA + 4 * j) =
          make_float4(va[4*j], va[4*j+1], va[4*j+2], va[4*j+3]);
  }
  if (half) {
    float* dstB = &rlds[colB * LSTR + cbB];
    #pragma unroll
    for (int j = 0; j < 4; ++j)
      *reinterpret_cast<float4*>(dstB + 4 * j) =
          make_float4(vb[4*j], vb[4*j+1], vb[4*j+2], vb[4*j+3]);
  }

  __syncthreads();

  // ---- gather: pure LDS + FMA (all globals already in registers) ----
  const float* rp[6];
  #pragma unroll
  for (int s = 0; s < 6; ++s) rp[s] = &rlds[jdx[s] * LSTR];

  float st[6] = {0.f, 0.f, 0.f, 0.f, 0.f, 0.f};
  GATHER_CHUNK(0)
  GATHER_CHUNK(16)
  GATHER_CHUNK(32)
  GATHER_CHUNK(48)

  // ---- epilogue: 2 intervals per thread, fully static ----
  #pragma unroll
  for (int ii = 0; ii < 2; ++ii) {
    const float a0 = st[3 * ii + 0] * TEMP_OVER_C;
    const float a1 = st[3 * ii + 1] * TEMP_OVER_C;
    const float a2 = st[3 * ii + 2] * TEMP_OVER_C;
    const float m  = fmaxf(a0, fmaxf(a1, a2));
    const float e0 = __expf(a0 - m);
    const float e1 = __expf(a1 - m);
    const float e2 = __expf(a2 - m);
    const float inv = 1.0f / (e0 + e1 + e2);
    const int iv = 2 * shalf + ii;
    const size_t o = ((size_t)(b * 4 + iv) * H_ + h) * W_ + w;
    out[o] = (nds[3 * ii] * e0 + nds[3 * ii + 1] * e1 + nds[3 * ii + 2] * e2) * inv;
    out[OUT_HALF + o] =
        (dsp[3 * ii] * e0 + dsp[3 * ii + 1] * e1 + dsp[3 * ii + 2] * e2) * inv;
  }
}

} // namespace

extern "C" void kernel_launch(void* const* d_in, const int* in_sizes, int n_in,
                              void* d_out, int out_size, void* d_ws, size_t ws_size,
                              hipStream_t stream) {
  const float* left  = (const float*)d_in[0];
  const float* right = (const float*)d_in[1];
  const float* disp  = (const float*)d_in[2];
  const float* ndisp = (const float*)d_in[3];
  float* out = (float*)d_out;
  dim3 grid(2 * B_ * H_);
  dim3 block(192);
  hipLaunchKernelGGL(fused_eval, grid, block, 0, stream, left, right, disp, ndisp, out);
}

// Round 10
// 14.737 us; speedup vs baseline: 1.1014x; 1.0437x over previous
//
#include <hip/hip_runtime.h>

namespace {

constexpr int B_ = 4, C_ = 64, H_ = 96, W_ = 192, S_ = 12;
constexpr int HW = H_ * W_;
constexpr float TEMP_OVER_C = 7.0f / 64.0f;   // TEMPERATURE / C
constexpr int OUT_HALF = B_ * 4 * H_ * W_;    // ndisp_out first, then disp_out
constexpr int LSTR = 68;                      // LDS row stride (floats): 68%32=4 -> bank spread

// Gather one 16-channel chunk for all 6 samples: 4 x ds_read_b128 each.
#define GATHER_CHUNK(LR, C0)                                              \
  {                                                                       \
    _Pragma("unroll")                                                     \
    for (int s = 0; s < 6; ++s) {                                         \
      const float* rr = rp[s] + (C0);                                     \
      const float4 r0 = *reinterpret_cast<const float4*>(rr);             \
      const float4 r1 = *reinterpret_cast<const float4*>(rr + 4);         \
      const float4 r2 = *reinterpret_cast<const float4*>(rr + 8);         \
      const float4 r3 = *reinterpret_cast<const float4*>(rr + 12);        \
      float a = st[s];                                                    \
      a = fmaf(LR[0],  r0.x, a);  a = fmaf(LR[1],  r0.y, a);              \
      a = fmaf(LR[2],  r0.z, a);  a = fmaf(LR[3],  r0.w, a);              \
      a = fmaf(LR[4],  r1.x, a);  a = fmaf(LR[5],  r1.y, a);              \
      a = fmaf(LR[6],  r1.z, a);  a = fmaf(LR[7],  r1.w, a);              \
      a = fmaf(LR[8],  r2.x, a);  a = fmaf(LR[9],  r2.y, a);              \
      a = fmaf(LR[10], r2.z, a);  a = fmaf(LR[11], r2.w, a);              \
      a = fmaf(LR[12], r3.x, a);  a = fmaf(LR[13], r3.y, a);              \
      a = fmaf(LR[14], r3.z, a);  a = fmaf(LR[15], r3.w, a);              \
      st[s] = a;                                                          \
    }                                                                     \
  }

__global__ __launch_bounds__(192) void fused_eval(
    const float* __restrict__ left, const float* __restrict__ right,
    const float* __restrict__ disp, const float* __restrict__ ndisp,
    float* __restrict__ out)
{
  __shared__ float rlds[144 * LSTR];   // 39168 B -> 4 blocks/CU

  // grid 768: bid and bid+384 are the two halves of one (b,h) row.
  // 384 % 8 == 0 -> both land on the same XCD slot under round-robin.
  const int bid = blockIdx.x;
  const int half = (bid >= 384) ? 1 : 0;
  const int bh = bid - half * 384;
  const int b = bh / H_;
  const int h = bh - b * H_;
  const int w0 = half * 96;
  const int s0g = half ? 48 : 0;          // first staged right column
  const int cnt = half ? 144 : 96;        // staged column count

  const int t = threadIdx.x;              // 0..191
  const int shalf = (t >= 96) ? 1 : 0;    // sample half: s 0..5 or 6..11
  const int wl = t - shalf * 96;          // 0..95
  const int w = w0 + wl;

  // ---- stage right[b, :, h, s0g:s0g+cnt] transposed into LDS [col][chan] ----
  // scalar global loads (coalesced across lanes), ds_write_b128 per 4 channels
  const float* rbase = right + (size_t)b * C_ * HW + (size_t)h * W_ + s0g;
  if (t < cnt) {
    float* dst = &rlds[t * LSTR];
    #pragma unroll
    for (int k = 0; k < 16; ++k) {
      float4 v;
      v.x = rbase[(size_t)(4 * k + 0) * HW + t];
      v.y = rbase[(size_t)(4 * k + 1) * HW + t];
      v.z = rbase[(size_t)(4 * k + 2) * HW + t];
      v.w = rbase[(size_t)(4 * k + 3) * HW + t];
      *reinterpret_cast<float4*>(dst + 4 * k) = v;
    }
  }

  // ---- per-thread sample setup + first left chunk (issue before barrier) ----
  const float* lcol = left + (size_t)b * C_ * HW + (size_t)h * W_ + w;
  float la[16], lb[16];
  #pragma unroll
  for (int c = 0; c < 16; ++c) la[c] = lcol[(size_t)c * HW];

  const int sb = 6 * shalf;
  float dsp[6], nds[6];
  int jdx[6];
  const size_t dbase = ((size_t)(b * S_ + sb) * H_ + h) * W_ + w;
  #pragma unroll
  for (int s = 0; s < 6; ++s) {
    dsp[s] = disp[dbase + (size_t)s * HW];
    nds[s] = ndisp[dbase + (size_t)s * HW];
    // reference: clip(w - d, 0, W-1) in f32, then int32 truncation
    const float ry = fminf(fmaxf((float)w - dsp[s], 0.0f), (float)(W_ - 1));
    jdx[s] = (int)ry - s0g;
  }

  __syncthreads();

  // ---- full 64-channel dot per thread, 6 samples, b128 LDS gathers ----
  const float* rp[6];
  #pragma unroll
  for (int s = 0; s < 6; ++s) rp[s] = &rlds[jdx[s] * LSTR];

  float st[6] = {0.f, 0.f, 0.f, 0.f, 0.f, 0.f};

  #pragma unroll
  for (int c = 0; c < 16; ++c) lb[c] = lcol[(size_t)(16 + c) * HW];
  GATHER_CHUNK(la, 0)
  #pragma unroll
  for (int c = 0; c < 16; ++c) la[c] = lcol[(size_t)(32 + c) * HW];
  GATHER_CHUNK(lb, 16)
  #pragma unroll
  for (int c = 0; c < 16; ++c) lb[c] = lcol[(size_t)(48 + c) * HW];
  GATHER_CHUNK(la, 32)
  GATHER_CHUNK(lb, 48)

  // ---- epilogue: 2 intervals per thread, fully static ----
  #pragma unroll
  for (int ii = 0; ii < 2; ++ii) {
    const float a0 = st[3 * ii + 0] * TEMP_OVER_C;
    const float a1 = st[3 * ii + 1] * TEMP_OVER_C;
    const float a2 = st[3 * ii + 2] * TEMP_OVER_C;
    const float m  = fmaxf(a0, fmaxf(a1, a2));
    const float e0 = __expf(a0 - m);
    const float e1 = __expf(a1 - m);
    const float e2 = __expf(a2 - m);
    const float inv = 1.0f / (e0 + e1 + e2);
    const int iv = 2 * shalf + ii;
    const size_t o = ((size_t)(b * 4 + iv) * H_ + h) * W_ + w;
    out[o] = (nds[3 * ii] * e0 + nds[3 * ii + 1] * e1 + nds[3 * ii + 2] * e2) * inv;
    out[OUT_HALF + o] =
        (dsp[3 * ii] * e0 + dsp[3 * ii + 1] * e1 + dsp[3 * ii + 2] * e2) * inv;
  }
}

} // namespace

extern "C" void kernel_launch(void* const* d_in, const int* in_sizes, int n_in,
                              void* d_out, int out_size, void* d_ws, size_t ws_size,
                              hipStream_t stream) {
  const float* left  = (const float*)d_in[0];
  const float* right = (const float*)d_in[1];
  const float* disp  = (const float*)d_in[2];
  const float* ndisp = (const float*)d_in[3];
  float* out = (float*)d_out;
  dim3 grid(2 * B_ * H_);
  dim3 block(192);
  hipLaunchKernelGGL(fused_eval, grid, block, 0, stream, left, right, disp, ndisp, out);
}